// Round 6
// baseline (737.526 us; speedup 1.0000x reference)
//
#include <hip/hip_runtime.h>
#include <hip/hip_bf16.h>

#define NN 50000
#define NE 800000
#define HD 128
#define G3 384   // 3*H
#define K2 256   // 2*H
#define PROWS 782  // ceil(NN/64) rows per partition
#define NT 49      // 16-row tiles per partition

typedef short s16x8 __attribute__((ext_vector_type(8)));
typedef float f32x4 __attribute__((ext_vector_type(4)));

static __device__ __forceinline__ ushort f2b(float f) {
    __hip_bfloat16 b = __float2bfloat16(f);
    return *(ushort*)&b;
}
static __device__ __forceinline__ float b2f(ushort u) {
    return __uint_as_float(((uint)u) << 16);
}

static __device__ __forceinline__ void gl_lds16(const void* g, void* l) {
    __builtin_amdgcn_global_load_lds(
        (const __attribute__((address_space(1))) uint*)(uintptr_t)g,
        (__attribute__((address_space(3))) uint*)(uintptr_t)l, 16, 0, 0);
}

// ---------------- CSR build ----------------
__global__ void k_deg(const int* __restrict__ edges, int* __restrict__ deg) {
    int e = blockIdx.x * blockDim.x + threadIdx.x;
    if (e < NE) atomicAdd(&deg[edges[2 * e + 1]], 1);
}

__global__ void k_off(const int* __restrict__ deg, int* __restrict__ off,
                      int* __restrict__ cur, int* __restrict__ counter) {
    int v = blockIdx.x * blockDim.x + threadIdx.x;
    if (v < NN) {
        int o = atomicAdd(counter, deg[v]);
        off[v] = o;
        cur[v] = o;
    }
}

__global__ void k_fill(const int* __restrict__ edges, int* __restrict__ cur,
                       int* __restrict__ csr_src) {
    int e = blockIdx.x * blockDim.x + threadIdx.x;
    if (e < NE) {
        int s = edges[2 * e];
        int d = edges[2 * e + 1];
        int pos = atomicAdd(&cur[d], 1);
        csr_src[pos] = s;
    }
}

// ---------------- combined weights (f32) ----------------
// B1[t][k][n] = sum_j W_ih[t][n][j] * W_msg[t][j][k]   (k<256, n<384)
__global__ void k_comb1(const float* __restrict__ W_ih, const float* __restrict__ W_msg,
                        float* __restrict__ B1) {
    int idx = blockIdx.x * blockDim.x + threadIdx.x;
    if (idx >= 2 * K2 * G3) return;
    int k = idx % K2;
    int n = (idx / K2) % G3;
    int t = idx / (K2 * G3);
    const float* wi = W_ih + ((size_t)t * G3 + n) * K2;
    const float* wm = W_msg + (size_t)t * K2 * K2;
    float acc = 0.f;
#pragma unroll 8
    for (int j = 0; j < K2; j++) acc += wi[j] * wm[(size_t)j * K2 + k];
    B1[((size_t)t * K2 + k) * G3 + n] = acc;
}

// c3[t][n] = sum_j W_ih[t][n][j] * b_msg[t][j]
__global__ void k_comb3(const float* __restrict__ W_ih, const float* __restrict__ b_msg,
                        float* __restrict__ c3) {
    int idx = blockIdx.x * blockDim.x + threadIdx.x;
    if (idx >= 2 * G3) return;
    int n = idx % G3;
    int t = idx / G3;
    const float* wi = W_ih + ((size_t)t * G3 + n) * K2;
    const float* bm = b_msg + t * K2;
    float acc = 0.f;
#pragma unroll 8
    for (int j = 0; j < K2; j++) acc += wi[j] * bm[j];
    c3[idx] = acc;
}

// ---------------- pack B per (t, quarter) (bf16) ----------------
// Bq[t][q][slot(96)][lane(64)][e(8)] ; slot = slab*24 + kb*6 + nf
// slab: 0=C1, 1=C2_hi, 2=C2_lo, 3=W_hh ; nf = gate*2+dn
// out col d = q*32 + dn*16 + (lane&15) ; frag k = kb*32 + (lane>>4)*8 + e
__global__ void k_pack4(const float* __restrict__ B1, const float* __restrict__ W_hh,
                        ushort* __restrict__ Bq) {
    int idx = blockIdx.x * blockDim.x + threadIdx.x;
    if (idx >= 2 * 4 * 96 * 64) return;
    int lane = idx & 63;
    int slotq = (idx >> 6) % 96;
    int qq = ((idx >> 6) / 96) % 4;
    int t = idx / (64 * 96 * 4);
    int slab = slotq / 24;
    int rem = slotq % 24;
    int kb = rem / 6, nf = rem % 6;
    int gate = nf >> 1, dn = nf & 1;
    int d = qq * 32 + dn * 16 + (lane & 15);
    int kbase = kb * 32 + (lane >> 4) * 8;
    ushort* dst = Bq + (size_t)idx * 8;
#pragma unroll
    for (int e = 0; e < 8; e++) {
        int k = kbase + e;  // 0..127 within slab
        float v;
        if (slab == 0) {
            v = B1[((size_t)t * K2 + k) * G3 + gate * 128 + d];
        } else if (slab == 3) {
            v = W_hh[((size_t)t * G3 + gate * 128 + d) * HD + k];
        } else {
            float full = B1[((size_t)t * K2 + 128 + k) * G3 + gate * 128 + d];
            v = (slab == 1) ? full : (full - b2f(f2b(full)));
        }
        dst[e] = f2b(v);
    }
}

// bias packs, each [t][q][nf(6)][16]
__global__ void k_packbias3(const float* __restrict__ b_ih, const float* __restrict__ b_hh,
                            const float* __restrict__ c3,
                            float* __restrict__ bih_p, float* __restrict__ bhh_p,
                            float* __restrict__ c3_p) {
    int idx = blockIdx.x * blockDim.x + threadIdx.x;
    if (idx >= 2 * 4 * 6 * 16) return;
    int c = idx & 15;
    int nf = (idx >> 4) % 6;
    int qq = ((idx >> 4) / 6) % 4;
    int t = idx / (16 * 6 * 4);
    int gate = nf >> 1, dn = nf & 1;
    int d = qq * 32 + dn * 16 + c;
    bih_p[idx] = b_ih[t * G3 + gate * 128 + d];
    bhh_p[idx] = b_hh[t * G3 + gate * 128 + d];
    c3_p[idx]  = c3[t * G3 + gate * 128 + d];
}

// ---------------- h f32 -> bf16 (for gathers) ----------------
__global__ void k_h2b(const float* __restrict__ h, ushort* __restrict__ hb) {
    int i = blockIdx.x * blockDim.x + threadIdx.x;
    if (i >= NN * HD / 4) return;
    float4 v = reinterpret_cast<const float4*>(h)[i];
    ushort4 o;
    o.x = f2b(v.x); o.y = f2b(v.y); o.z = f2b(v.z); o.w = f2b(v.w);
    reinterpret_cast<ushort4*>(hb)[i] = o;
}

// ---------------- prep: A rows [s | (deg*h)_hi | (deg*h)_lo | h_hi] bf16 ----------------
__global__ void k_prep(const ushort* __restrict__ hb, const float* __restrict__ hf,
                       const int* __restrict__ off, const int* __restrict__ deg,
                       const int* __restrict__ csr, ushort* __restrict__ Abf) {
    int wv = (blockIdx.x * blockDim.x + threadIdx.x) >> 6;
    int lane = threadIdx.x & 63;
    if (wv >= NN) return;
    int st = off[wv];
    int dg = deg[wv];
    float a0 = 0.f, a1 = 0.f;
    int j = 0;
    for (; j + 8 <= dg; j += 8) {
        uint v[8];
#pragma unroll
        for (int qq = 0; qq < 8; qq++) {
            int s = csr[st + j + qq];
            v[qq] = *reinterpret_cast<const uint*>(hb + (size_t)s * HD + lane * 2);
        }
#pragma unroll
        for (int qq = 0; qq < 8; qq++) {
            a0 += b2f((ushort)(v[qq] & 0xffff));
            a1 += b2f((ushort)(v[qq] >> 16));
        }
    }
    for (; j < dg; j++) {
        int s = csr[st + j];
        uint v = *reinterpret_cast<const uint*>(hb + (size_t)s * HD + lane * 2);
        a0 += b2f((ushort)(v & 0xffff));
        a1 += b2f((ushort)(v >> 16));
    }
    uint* arow = reinterpret_cast<uint*>(Abf + (size_t)wv * 512);
    arow[lane] = (uint)f2b(a0) | ((uint)f2b(a1) << 16);
    float2 hv = *reinterpret_cast<const float2*>(hf + (size_t)wv * HD + lane * 2);
    float dgf = (float)dg;
    float dh0 = dgf * hv.x, dh1 = dgf * hv.y;
    ushort p0 = f2b(dh0), p1 = f2b(dh1);
    ushort l0 = f2b(dh0 - b2f(p0)), l1 = f2b(dh1 - b2f(p1));
    arow[64 + lane]  = (uint)p0 | ((uint)p1 << 16);
    arow[128 + lane] = (uint)l0 | ((uint)l1 << 16);
    arow[192 + lane] = (uint)f2b(hv.x) | ((uint)f2b(hv.y) << 16);
}

// ---------------- persistent-B fused MFMA GEMM + GRU (no inner barriers) ----------------
// grid = 256 blocks (64 partitions x 4 d-quarters, XCD-co-located), 512 threads (8 waves).
// Block loads its 96KB B quarter into LDS once; each wave streams 16-row tiles
// independently with double-buffered A prefetch. No __syncthreads in the loop.

#define BSr(slab, kb, nf) \
    (*reinterpret_cast<const s16x8*>(&Bs[(size_t)((((slab) * 24 + (kb) * 6 + (nf)) * 64 + lane)) * 8]))

#define LOADA(P, tile_)                                                          \
    {                                                                            \
        int row_ = pbase + (tile_) * 16 + col;                                   \
        if (row_ >= NN) row_ = NN - 1;                                           \
        const s16x8* ap_ = reinterpret_cast<const s16x8*>(Abf + (size_t)row_ * 512); \
        _Pragma("unroll") for (int kb = 0; kb < 4; kb++) {                       \
            P##s[kb]  = ap_[kb * 4 + lhi];                                       \
            P##hh[kb] = ap_[16 + kb * 4 + lhi];                                  \
            P##hl[kb] = ap_[32 + kb * 4 + lhi];                                  \
            P##h[kb]  = ap_[48 + kb * 4 + lhi];                                  \
        }                                                                        \
    }

#define EPI(tile_)                                                               \
    {                                                                            \
        int rb0 = pbase + (tile_) * 16 + (lhi << 2);                             \
        _Pragma("unroll") for (int r = 0; r < 4; r++) {                          \
            int m = rb0 + r;                                                     \
            bool wr = m < NN;                                                    \
            int mm = wr ? m : 0;                                                 \
            int dgi = deg[mm];                                                   \
            float dgf = (float)dgi;                                              \
            _Pragma("unroll") for (int dn = 0; dn < 2; dn++) {                   \
                int d = (q << 5) + (dn << 4) + col;                              \
                float hv = hcur[(size_t)mm * HD + d];                            \
                float ir  = accI[0 + dn][r] + dgf * c3v[0][dn] + bihv[0][dn];    \
                float iz  = accI[2 + dn][r] + dgf * c3v[1][dn] + bihv[1][dn];    \
                float in_ = accI[4 + dn][r] + dgf * c3v[2][dn] + bihv[2][dn];    \
                float hr = accH[0 + dn][r] + bhhv[0][dn];                        \
                float hz = accH[2 + dn][r] + bhhv[1][dn];                        \
                float hn = accH[4 + dn][r] + bhhv[2][dn];                        \
                float rg = 1.f / (1.f + expf(-(ir + hr)));                       \
                float zg = 1.f / (1.f + expf(-(iz + hz)));                       \
                float ng = tanhf(in_ + rg * hn);                                 \
                float hnew = (1.f - zg) * ng + zg * hv;                          \
                float res = (dgi > 0) ? hnew : hv;                               \
                if (wr) {                                                        \
                    hout[(size_t)m * HD + d] = res;                              \
                    hb_out[(size_t)m * HD + d] = f2b(res);                       \
                }                                                                \
            }                                                                    \
        }                                                                        \
    }

#define COMPUTE(P, tile_)                                                        \
    {                                                                            \
        f32x4 accI[6], accH[6];                                                  \
        _Pragma("unroll") for (int i = 0; i < 6; i++) {                          \
            accI[i] = f32x4{0.f, 0.f, 0.f, 0.f};                                 \
            accH[i] = f32x4{0.f, 0.f, 0.f, 0.f};                                 \
        }                                                                        \
        _Pragma("unroll") for (int kb = 0; kb < 4; kb++) {                       \
            _Pragma("unroll") for (int nf = 0; nf < 6; nf++) {                   \
                s16x8 b0 = BSr(0, kb, nf);                                       \
                accI[nf] = __builtin_amdgcn_mfma_f32_16x16x32_bf16(P##s[kb], b0, accI[nf], 0, 0, 0); \
                s16x8 b1 = BSr(1, kb, nf);                                       \
                accI[nf] = __builtin_amdgcn_mfma_f32_16x16x32_bf16(P##hh[kb], b1, accI[nf], 0, 0, 0); \
                accI[nf] = __builtin_amdgcn_mfma_f32_16x16x32_bf16(P##hl[kb], b1, accI[nf], 0, 0, 0); \
                s16x8 b2 = BSr(2, kb, nf);                                       \
                accI[nf] = __builtin_amdgcn_mfma_f32_16x16x32_bf16(P##hh[kb], b2, accI[nf], 0, 0, 0); \
                s16x8 b3 = BSr(3, kb, nf);                                       \
                accH[nf] = __builtin_amdgcn_mfma_f32_16x16x32_bf16(P##h[kb], b3, accH[nf], 0, 0, 0); \
            }                                                                    \
        }                                                                        \
        EPI(tile_)                                                               \
    }

__global__ __launch_bounds__(512) void k_fused(
    const ushort* __restrict__ Abf,     // [NN][512] bf16
    const ushort* __restrict__ Bq_t,    // [4][96][512] bf16 (this t)
    const float* __restrict__ bih_t,    // [4][6][16]
    const float* __restrict__ bhh_t,
    const float* __restrict__ c3_t,
    const int* __restrict__ deg,
    const float* __restrict__ hcur,     // [NN][128] f32
    float* __restrict__ hout,           // [NN][128] f32
    ushort* __restrict__ hb_out)        // [NN][128] bf16
{
    __shared__ __align__(16) ushort Bs[96 * 512];

    int tid = threadIdx.x;
    int bid = blockIdx.x;
    int xcd = bid & 7;
    int slot = bid >> 3;
    int p = xcd * 8 + (slot >> 2);   // all 4 quarters of partition p on one XCD
    int q = slot & 3;
    int w = tid >> 6, lane = tid & 63, lhi = lane >> 4, col = lane & 15;
    int pbase = p * PROWS;

    // stage B quarter (96 x 1KB segments), wave w loads 12
    const ushort* Bg = Bq_t + (size_t)q * 96 * 512;
#pragma unroll
    for (int i = 0; i < 12; i++) {
        int seg = w * 12 + i;
        gl_lds16(Bg + (size_t)seg * 512 + lane * 8, &Bs[(size_t)seg * 512]);
    }

    float bihv[3][2], bhhv[3][2], c3v[3][2];
#pragma unroll
    for (int g = 0; g < 3; g++)
#pragma unroll
        for (int dn = 0; dn < 2; dn++) {
            int o = (q * 6 + g * 2 + dn) * 16 + col;
            bihv[g][dn] = bih_t[o];
            bhhv[g][dn] = bhh_t[o];
            c3v[g][dn] = c3_t[o];
        }
    __syncthreads();   // drains gl_lds vmcnt; only barrier in the kernel

    s16x8 As[4], Ahh[4], Ahl[4], Ah[4];
    s16x8 Cs[4], Chh[4], Chl[4], Ch[4];

    int tile = w;
    if (tile < NT) {
        LOADA(A, tile)
        while (true) {
            int tn = tile + 8;
            if (tn < NT) { LOADA(C, tn) }
            COMPUTE(A, tile)
            if (tn >= NT) break;
            tile = tn;
            tn = tile + 8;
            if (tn < NT) { LOADA(A, tn) }
            COMPUTE(C, tile)
            if (tn >= NT) break;
            tile = tn;
        }
    }
}

extern "C" void kernel_launch(void* const* d_in, const int* in_sizes, int n_in,
                              void* d_out, int out_size, void* d_ws, size_t ws_size,
                              hipStream_t stream) {
    const float* h_in  = (const float*)d_in[0];
    const int*   edges = (const int*)d_in[1];
    const float* W_msg = (const float*)d_in[2];
    const float* b_msg = (const float*)d_in[3];
    const float* W_ih  = (const float*)d_in[4];
    const float* W_hh  = (const float*)d_in[5];
    const float* b_ih  = (const float*)d_in[6];
    const float* b_hh  = (const float*)d_in[7];
    float* out = (float*)d_out;

    char* p = (char*)d_ws;
    auto alloc = [&](size_t bytes) {
        void* r = (void*)p;
        p += (bytes + 255) / 256 * 256;
        return r;
    };
    int*    deg     = (int*)alloc((size_t)(NN + 1) * 4);  // +1: counter
    int*    off     = (int*)alloc((size_t)NN * 4);
    int*    cur     = (int*)alloc((size_t)NN * 4);
    int*    csr_src = (int*)alloc((size_t)NE * 4);
    float*  B1      = (float*)alloc((size_t)2 * K2 * G3 * 4);
    float*  c3      = (float*)alloc((size_t)2 * G3 * 4);
    ushort* Bq      = (ushort*)alloc((size_t)2 * 4 * 96 * 512 * 2);
    float*  bih_p   = (float*)alloc((size_t)2 * 4 * 6 * 16 * 4);
    float*  bhh_p   = (float*)alloc((size_t)2 * 4 * 6 * 16 * 4);
    float*  c3_p    = (float*)alloc((size_t)2 * 4 * 6 * 16 * 4);
    ushort* hb0     = (ushort*)alloc((size_t)NN * HD * 2);
    ushort* hb1     = (ushort*)alloc((size_t)NN * HD * 2);
    ushort* Abf     = (ushort*)alloc((size_t)NN * 512 * 2);
    float*  h1      = (float*)alloc((size_t)NN * HD * 4);
    int*    counter = deg + NN;

    hipMemsetAsync(deg, 0, (size_t)(NN + 1) * 4, stream);
    k_deg<<<(NE + 255) / 256, 256, 0, stream>>>(edges, deg);
    k_off<<<(NN + 255) / 256, 256, 0, stream>>>(deg, off, cur, counter);
    k_fill<<<(NE + 255) / 256, 256, 0, stream>>>(edges, cur, csr_src);
    k_comb1<<<(2 * K2 * G3 + 255) / 256, 256, 0, stream>>>(W_ih, W_msg, B1);
    k_comb3<<<(2 * G3 + 255) / 256, 256, 0, stream>>>(W_ih, b_msg, c3);
    k_pack4<<<(2 * 4 * 96 * 64 + 255) / 256, 256, 0, stream>>>(B1, W_hh, Bq);
    k_packbias3<<<(2 * 4 * 6 * 16 + 255) / 256, 256, 0, stream>>>(b_ih, b_hh, c3,
                                                                  bih_p, bhh_p, c3_p);
    k_h2b<<<(NN * HD / 4 + 255) / 256, 256, 0, stream>>>(h_in, hb0);

    const size_t BqT = (size_t)4 * 96 * 512;  // ushorts per t
    const size_t biasT = (size_t)4 * 6 * 16;

    // step 0
    k_prep<<<(NN * 64 + 255) / 256, 256, 0, stream>>>(hb0, h_in, off, deg, csr_src, Abf);
    k_fused<<<256, 512, 0, stream>>>(Abf, Bq, bih_p, bhh_p, c3_p, deg, h_in, h1, hb1);
    // step 1 (hb_out reuses hb0; it is rebuilt by k_h2b every launch)
    k_prep<<<(NN * 64 + 255) / 256, 256, 0, stream>>>(hb1, h1, off, deg, csr_src, Abf);
    k_fused<<<256, 512, 0, stream>>>(Abf, Bq + BqT, bih_p + biasT, bhh_p + biasT,
                                     c3_p + biasT, deg, h1, out, hb0);
}

// Round 7
// 506.258 us; speedup vs baseline: 1.4568x; 1.4568x over previous
//
#include <hip/hip_runtime.h>
#include <hip/hip_bf16.h>

#define NN 50000
#define NE 800000
#define HD 128
#define G3 384   // 3*H
#define K2 256   // 2*H
#define NTILES 3125  // NN/16 exactly

typedef short s16x8 __attribute__((ext_vector_type(8)));
typedef float f32x4 __attribute__((ext_vector_type(4)));

static __device__ __forceinline__ ushort f2b(float f) {
    __hip_bfloat16 b = __float2bfloat16(f);
    return *(ushort*)&b;
}
static __device__ __forceinline__ float b2f(ushort u) {
    return __uint_as_float(((uint)u) << 16);
}
static __device__ __forceinline__ uint pk(ushort a, ushort b) {
    return (uint)a | ((uint)b << 16);
}

static __device__ __forceinline__ void gl_lds16(const void* g, void* l) {
    __builtin_amdgcn_global_load_lds(
        (const __attribute__((address_space(1))) uint*)(uintptr_t)g,
        (__attribute__((address_space(3))) uint*)(uintptr_t)l, 16, 0, 0);
}

// ---------------- CSR build ----------------
__global__ void k_deg(const int* __restrict__ edges, int* __restrict__ deg) {
    int e = blockIdx.x * blockDim.x + threadIdx.x;
    if (e < NE) atomicAdd(&deg[edges[2 * e + 1]], 1);
}

__global__ void k_off(const int* __restrict__ deg, int* __restrict__ off,
                      int* __restrict__ cur, int* __restrict__ counter) {
    int v = blockIdx.x * blockDim.x + threadIdx.x;
    if (v < NN) {
        int o = atomicAdd(counter, deg[v]);
        off[v] = o;
        cur[v] = o;
    }
}

__global__ void k_fill(const int* __restrict__ edges, int* __restrict__ cur,
                       int* __restrict__ csr_src) {
    int e = blockIdx.x * blockDim.x + threadIdx.x;
    if (e < NE) {
        int s = edges[2 * e];
        int d = edges[2 * e + 1];
        int pos = atomicAdd(&cur[d], 1);
        csr_src[pos] = s;
    }
}

// ---------------- combined weights (f32) ----------------
// B1[t][k][n] = sum_j W_ih[t][n][j] * W_msg[t][j][k]   (k<256, n<384)
__global__ void k_comb1(const float* __restrict__ W_ih, const float* __restrict__ W_msg,
                        float* __restrict__ B1) {
    int idx = blockIdx.x * blockDim.x + threadIdx.x;
    if (idx >= 2 * K2 * G3) return;
    int k = idx % K2;
    int n = (idx / K2) % G3;
    int t = idx / (K2 * G3);
    const float* wi = W_ih + ((size_t)t * G3 + n) * K2;
    const float* wm = W_msg + (size_t)t * K2 * K2;
    float acc = 0.f;
#pragma unroll 8
    for (int j = 0; j < K2; j++) acc += wi[j] * wm[(size_t)j * K2 + k];
    B1[((size_t)t * K2 + k) * G3 + n] = acc;
}

// c3[t][n] = sum_j W_ih[t][n][j] * b_msg[t][j]
__global__ void k_comb3(const float* __restrict__ W_ih, const float* __restrict__ b_msg,
                        float* __restrict__ c3) {
    int idx = blockIdx.x * blockDim.x + threadIdx.x;
    if (idx >= 2 * G3) return;
    int n = idx % G3;
    int t = idx / G3;
    const float* wi = W_ih + ((size_t)t * G3 + n) * K2;
    const float* bm = b_msg + t * K2;
    float acc = 0.f;
#pragma unroll 8
    for (int j = 0; j < K2; j++) acc += wi[j] * bm[j];
    c3[idx] = acc;
}

// ---------------- pack B into linear MFMA stream (bf16) ----------------
// Bc[t][dhalf][slot(192)][lane(64)][e(8)]  (identical to round 5)
__global__ void k_pack3(const float* __restrict__ B1, const float* __restrict__ W_hh,
                        ushort* __restrict__ Bc) {
    int idx = blockIdx.x * blockDim.x + threadIdx.x;
    if (idx >= 2 * 2 * 192 * 64) return;
    int lane = idx & 63;
    int slot = (idx >> 6) % 192;
    int dhalf = ((idx >> 6) / 192) % 2;
    int t = idx / (64 * 192 * 2);
    int g = slot / 12, n = slot % 12;
    int mode, kb;  // 0=C1, 1=C2_hi, 2=W_hh, 3=C2_lo
    if (g < 4) { mode = 0; kb = g; }
    else {
        int q = (g - 4) / 3, r = (g - 4) % 3;
        kb = q;
        mode = (r == 0) ? 1 : ((r == 1) ? 2 : 3);
    }
    int gate = n >> 2, dn = n & 3;
    int d = dhalf * 64 + dn * 16 + (lane & 15);
    int kbase = kb * 32 + (lane >> 4) * 8;
    ushort* dst = Bc + (size_t)idx * 8;
#pragma unroll
    for (int e = 0; e < 8; e++) {
        int k = kbase + e;  // 0..127 within slab
        float v;
        if (mode == 0) {
            v = B1[((size_t)t * K2 + k) * G3 + gate * 128 + d];
        } else if (mode == 2) {
            v = W_hh[((size_t)t * G3 + gate * 128 + d) * HD + k];
        } else {
            float full = B1[((size_t)t * K2 + 128 + k) * G3 + gate * 128 + d];
            v = (mode == 1) ? full : (full - b2f(f2b(full)));
        }
        dst[e] = f2b(v);
    }
}

// bias packs, each [t][dhalf][12][16]
__global__ void k_packbias2(const float* __restrict__ b_ih, const float* __restrict__ b_hh,
                            const float* __restrict__ c3,
                            float* __restrict__ bih_p, float* __restrict__ bhh_p,
                            float* __restrict__ c3_p) {
    int idx = blockIdx.x * blockDim.x + threadIdx.x;
    if (idx >= 2 * 2 * 12 * 16) return;
    int c = idx & 15;
    int n = (idx >> 4) % 12;
    int dhalf = ((idx >> 4) / 12) % 2;
    int t = idx / (16 * 12 * 2);
    int g = n >> 2, dn = n & 3;
    int d = dhalf * 64 + dn * 16 + c;
    bih_p[idx] = b_ih[t * G3 + g * 128 + d];
    bhh_p[idx] = b_hh[t * G3 + g * 128 + d];
    c3_p[idx]  = c3[t * G3 + g * 128 + d];
}

// ---------------- h f32 -> bf16 (for gathers) ----------------
__global__ void k_h2b(const float* __restrict__ h, ushort* __restrict__ hb) {
    int i = blockIdx.x * blockDim.x + threadIdx.x;
    if (i >= NN * HD / 4) return;
    float4 v = reinterpret_cast<const float4*>(h)[i];
    ushort4 o;
    o.x = f2b(v.x); o.y = f2b(v.y); o.z = f2b(v.z); o.w = f2b(v.w);
    reinterpret_cast<ushort4*>(hb)[i] = o;
}

// ---------------- prep: gather + write A in MFMA FRAGMENT order ----------------
// FA[tile(3125)][slab(4)][kb(4)][lane(64)][e(8)] bf16
// slab: 0=s, 1=(deg*h)_hi, 2=(deg*h)_lo, 3=h_hi
// node wv = tile*16 + r holds elements k=2*lane,2*lane+1 of each slab:
//   kb = lane>>4 ; lane' = r + 16*((lane&15)>>2) ; uint idx = lane'*4 + (lane&3)
__global__ void k_prep(const ushort* __restrict__ hb, const float* __restrict__ hf,
                       const int* __restrict__ off, const int* __restrict__ deg,
                       const int* __restrict__ csr, ushort* __restrict__ FA) {
    int wv = (blockIdx.x * blockDim.x + threadIdx.x) >> 6;
    int lane = threadIdx.x & 63;
    if (wv >= NN) return;
    int st = off[wv];
    int dg = deg[wv];
    float a0 = 0.f, a1 = 0.f;
    int j = 0;
    for (; j + 16 <= dg; j += 16) {
        uint v[16];
#pragma unroll
        for (int q = 0; q < 16; q++) {
            int s = csr[st + j + q];
            v[q] = *reinterpret_cast<const uint*>(hb + (size_t)s * HD + lane * 2);
        }
#pragma unroll
        for (int q = 0; q < 16; q++) {
            a0 += b2f((ushort)(v[q] & 0xffff));
            a1 += b2f((ushort)(v[q] >> 16));
        }
    }
    for (; j + 4 <= dg; j += 4) {
        uint v[4];
#pragma unroll
        for (int q = 0; q < 4; q++) {
            int s = csr[st + j + q];
            v[q] = *reinterpret_cast<const uint*>(hb + (size_t)s * HD + lane * 2);
        }
#pragma unroll
        for (int q = 0; q < 4; q++) {
            a0 += b2f((ushort)(v[q] & 0xffff));
            a1 += b2f((ushort)(v[q] >> 16));
        }
    }
    for (; j < dg; j++) {
        int s = csr[st + j];
        uint v = *reinterpret_cast<const uint*>(hb + (size_t)s * HD + lane * 2);
        a0 += b2f((ushort)(v & 0xffff));
        a1 += b2f((ushort)(v >> 16));
    }
    int tile = wv >> 4, r = wv & 15;
    int kb = lane >> 4;
    int lp = r + (((lane & 15) >> 2) << 4);
    // uint base of this tile (8192 elems = 4096 uints), frag = 256 uints, slab = 1024
    uint* base = reinterpret_cast<uint*>(FA) + (size_t)tile * 4096 + kb * 256 +
                 lp * 4 + (lane & 3);
    float2 hv = *reinterpret_cast<const float2*>(hf + (size_t)wv * HD + lane * 2);
    float dgf = (float)dg;
    float dh0 = dgf * hv.x, dh1 = dgf * hv.y;
    ushort p0 = f2b(dh0), p1 = f2b(dh1);
    ushort l0 = f2b(dh0 - b2f(p0)), l1 = f2b(dh1 - b2f(p1));
    base[0]    = pk(f2b(a0), f2b(a1));        // slab 0: s
    base[1024] = pk(p0, p1);                  // slab 1: dh_hi
    base[2048] = pk(l0, l1);                  // slab 2: dh_lo
    base[3072] = pk(f2b(hv.x), f2b(hv.y));    // slab 3: h_hi
}

// ---------------- fused MFMA GEMM + GRU: frag-order A (coalesced) + LDS B ----------------
// grid (782, 2); block 256 (4 waves); wave owns 16 rows x its d-half.
// B streamed through LDS in 8 double-buffered chunks of 24 slots (24KB each).
#define STAGE(c)                                                          \
    _Pragma("unroll") for (int i = 0; i < 6; i++) {                       \
        int seg = w * 6 + i;                                              \
        gl_lds16(Bg + (size_t)(c) * 12288 + seg * 512 + lane * 8,         \
                 &Bs[(c) & 1][seg * 512]);                                \
    }

// A-frag fid = slab*4 + kb : one contiguous 1KB load (16B/lane)
#define AF(fid) (*reinterpret_cast<const s16x8*>(FAt + ((size_t)(fid) * 64 + lane) * 8))

#define GROUP(p, f1, dual, f2, ACC)                                       \
    do {                                                                  \
        s16x8 a1 = AF(f1);                                                \
        s16x8 a2 = (dual) ? AF(f2) : a1;                                  \
        _Pragma("unroll") for (int n = 0; n < 12; n++) {                  \
            s16x8 b = *reinterpret_cast<const s16x8*>(                    \
                &bufc[((p) * 12 + n) * 512 + lane * 8]);                  \
            ACC[n] = __builtin_amdgcn_mfma_f32_16x16x32_bf16(a1, b, ACC[n], 0, 0, 0); \
            if (dual)                                                     \
                ACC[n] = __builtin_amdgcn_mfma_f32_16x16x32_bf16(a2, b, ACC[n], 0, 0, 0); \
        }                                                                 \
    } while (0)

#define CHUNK(c, ...)                                                     \
    {                                                                     \
        if ((c) < 7) { STAGE((c) + 1); }                                  \
        const ushort* bufc = &Bs[(c) & 1][0];                             \
        __VA_ARGS__                                                       \
        __syncthreads();                                                  \
    }

__global__ __launch_bounds__(256) void k_fused(
    const ushort* __restrict__ FA,      // [3125][16][64][8] bf16 frag-order A
    const ushort* __restrict__ Bc_t,    // [dhalf][192][512] bf16 (this t)
    const float* __restrict__ bih_t,    // [dhalf][12][16]
    const float* __restrict__ bhh_t,
    const float* __restrict__ c3_t,
    const int* __restrict__ deg,
    const float* __restrict__ hcur,     // [NN][128] f32
    float* __restrict__ hout,           // [NN][128] f32
    ushort* __restrict__ hb_out)        // [NN][128] bf16
{
    __shared__ __align__(16) ushort Bs[2][24 * 512];

    int tid = threadIdx.x;
    int m0 = blockIdx.x * 64;
    int dhalf = blockIdx.y;
    int w = tid >> 6;
    int lane = tid & 63;
    int lhi = lane >> 4;
    int col = lane & 15;
    int rowbase = m0 + w * 16;

    int tile = rowbase >> 4;
    int tclamp = tile < NTILES ? tile : NTILES - 1;
    const ushort* FAt = FA + (size_t)tclamp * 8192;
    const ushort* Bg = Bc_t + (size_t)dhalf * 192 * 512;

    f32x4 accI[12], accH[12];
#pragma unroll
    for (int i = 0; i < 12; i++) {
        accI[i] = f32x4{0.f, 0.f, 0.f, 0.f};
        accH[i] = f32x4{0.f, 0.f, 0.f, 0.f};
    }

    // prologue: stage chunk 0 (syncthreads drains vmcnt before barrier)
    STAGE(0);
    __syncthreads();

    // fid = slab*4+kb : slab 0=s, 1=dh_hi, 2=dh_lo, 3=h_hi
    CHUNK(0, GROUP(0, 0, 0, 0, accI); GROUP(1, 1, 0, 0, accI);)     // C1 k0, C1 k1
    CHUNK(1, GROUP(0, 2, 0, 0, accI); GROUP(1, 3, 0, 0, accI);)     // C1 k2, C1 k3
    CHUNK(2, GROUP(0, 4, 1, 8, accI); GROUP(1, 12, 0, 0, accH);)    // C2hi k0 (dual dh_lo), Whh k0
    CHUNK(3, GROUP(0, 4, 0, 0, accI); GROUP(1, 5, 1, 9, accI);)     // C2lo k0 (x dh_hi), C2hi k1
    CHUNK(4, GROUP(0, 13, 0, 0, accH); GROUP(1, 5, 0, 0, accI);)    // Whh k1, C2lo k1
    CHUNK(5, GROUP(0, 6, 1, 10, accI); GROUP(1, 14, 0, 0, accH);)   // C2hi k2, Whh k2
    CHUNK(6, GROUP(0, 6, 0, 0, accI); GROUP(1, 7, 1, 11, accI);)    // C2lo k2, C2hi k3
    CHUNK(7, GROUP(0, 15, 0, 0, accH); GROUP(1, 7, 0, 0, accI);)    // Whh k3, C2lo k3

    // epilogue: GRU in-register
    float bih[3][4], bhh[3][4], c3v[3][4];
#pragma unroll
    for (int g = 0; g < 3; g++)
#pragma unroll
        for (int dn = 0; dn < 4; dn++) {
            int o = (dhalf * 12 + g * 4 + dn) * 16 + col;
            bih[g][dn] = bih_t[o];
            bhh[g][dn] = bhh_t[o];
            c3v[g][dn] = c3_t[o];
        }

    int rbase0 = rowbase + (lhi << 2);
#pragma unroll
    for (int r = 0; r < 4; r++) {
        int m = rbase0 + r;
        bool wr = m < NN;
        int mm = wr ? m : 0;
        int dgi = deg[mm];
        float dgf = (float)dgi;
#pragma unroll
        for (int dn = 0; dn < 4; dn++) {
            int d = (dhalf << 6) + (dn << 4) + col;
            float hv = hcur[(size_t)mm * HD + d];
            float ir  = accI[dn][r]     + dgf * c3v[0][dn] + bih[0][dn];
            float iz  = accI[4 + dn][r] + dgf * c3v[1][dn] + bih[1][dn];
            float in_ = accI[8 + dn][r] + dgf * c3v[2][dn] + bih[2][dn];
            float hr = accH[dn][r]     + bhh[0][dn];
            float hz = accH[4 + dn][r] + bhh[1][dn];
            float hn = accH[8 + dn][r] + bhh[2][dn];
            float rg = 1.f / (1.f + expf(-(ir + hr)));
            float zg = 1.f / (1.f + expf(-(iz + hz)));
            float ng = tanhf(in_ + rg * hn);
            float hnew = (1.f - zg) * ng + zg * hv;
            float res = (dgi > 0) ? hnew : hv;
            if (wr) {
                hout[(size_t)m * HD + d] = res;
                hb_out[(size_t)m * HD + d] = f2b(res);
            }
        }
    }
}

extern "C" void kernel_launch(void* const* d_in, const int* in_sizes, int n_in,
                              void* d_out, int out_size, void* d_ws, size_t ws_size,
                              hipStream_t stream) {
    const float* h_in  = (const float*)d_in[0];
    const int*   edges = (const int*)d_in[1];
    const float* W_msg = (const float*)d_in[2];
    const float* b_msg = (const float*)d_in[3];
    const float* W_ih  = (const float*)d_in[4];
    const float* W_hh  = (const float*)d_in[5];
    const float* b_ih  = (const float*)d_in[6];
    const float* b_hh  = (const float*)d_in[7];
    float* out = (float*)d_out;

    char* p = (char*)d_ws;
    auto alloc = [&](size_t bytes) {
        void* r = (void*)p;
        p += (bytes + 255) / 256 * 256;
        return r;
    };
    int*    deg     = (int*)alloc((size_t)(NN + 1) * 4);  // +1: counter
    int*    off     = (int*)alloc((size_t)NN * 4);
    int*    cur     = (int*)alloc((size_t)NN * 4);
    int*    csr_src = (int*)alloc((size_t)NE * 4);
    float*  B1      = (float*)alloc((size_t)2 * K2 * G3 * 4);
    float*  c3      = (float*)alloc((size_t)2 * G3 * 4);
    ushort* Bc      = (ushort*)alloc((size_t)2 * 2 * 192 * 512 * 2);
    float*  bih_p   = (float*)alloc((size_t)2 * 2 * 12 * 16 * 4);
    float*  bhh_p   = (float*)alloc((size_t)2 * 2 * 12 * 16 * 4);
    float*  c3_p    = (float*)alloc((size_t)2 * 2 * 12 * 16 * 4);
    ushort* hb0     = (ushort*)alloc((size_t)NN * HD * 2);
    ushort* hb1     = (ushort*)alloc((size_t)NN * HD * 2);
    ushort* FA      = (ushort*)alloc((size_t)NTILES * 8192 * 2);
    float*  h1      = (float*)alloc((size_t)NN * HD * 4);
    int*    counter = deg + NN;

    hipMemsetAsync(deg, 0, (size_t)(NN + 1) * 4, stream);
    k_deg<<<(NE + 255) / 256, 256, 0, stream>>>(edges, deg);
    k_off<<<(NN + 255) / 256, 256, 0, stream>>>(deg, off, cur, counter);
    k_fill<<<(NE + 255) / 256, 256, 0, stream>>>(edges, cur, csr_src);
    k_comb1<<<(2 * K2 * G3 + 255) / 256, 256, 0, stream>>>(W_ih, W_msg, B1);
    k_comb3<<<(2 * G3 + 255) / 256, 256, 0, stream>>>(W_ih, b_msg, c3);
    k_pack3<<<(2 * 2 * 192 * 64 + 255) / 256, 256, 0, stream>>>(B1, W_hh, Bc);
    k_packbias2<<<(2 * 2 * 12 * 16 + 255) / 256, 256, 0, stream>>>(b_ih, b_hh, c3,
                                                                   bih_p, bhh_p, c3_p);
    k_h2b<<<(NN * HD / 4 + 255) / 256, 256, 0, stream>>>(h_in, hb0);

    dim3 fgrid((NN + 63) / 64, 2);
    const size_t BcT = (size_t)2 * 192 * 512;   // ushort units per t
    const size_t biasT = (size_t)2 * 12 * 16;

    // step 0
    k_prep<<<(NN * 64 + 255) / 256, 256, 0, stream>>>(hb0, h_in, off, deg, csr_src, FA);
    k_fused<<<fgrid, 256, 0, stream>>>(FA, Bc, bih_p, bhh_p, c3_p, deg, h_in, h1, hb1);
    // step 1 (hb_out reuses hb0; it is rebuilt by k_h2b every launch)
    k_prep<<<(NN * 64 + 255) / 256, 256, 0, stream>>>(hb1, h1, off, deg, csr_src, FA);
    k_fused<<<fgrid, 256, 0, stream>>>(FA, Bc + BcT, bih_p + biasT, bhh_p + biasT,
                                       c3_p + biasT, deg, h1, out, hb0);
}

// Round 9
// 343.050 us; speedup vs baseline: 2.1499x; 1.4758x over previous
//
#include <hip/hip_runtime.h>
#include <hip/hip_bf16.h>

#define NN 50000
#define NE 800000
#define HD 128
#define G3 384   // 3*H
#define K2 256   // 2*H
#define NTILES 3125  // NN/16 exactly
#define NGRP 782     // 64-row groups

typedef short s16x8 __attribute__((ext_vector_type(8)));
typedef float f32x4 __attribute__((ext_vector_type(4)));

static __device__ __forceinline__ ushort f2b(float f) {
    __hip_bfloat16 b = __float2bfloat16(f);
    return *(ushort*)&b;
}
static __device__ __forceinline__ float b2f(ushort u) {
    return __uint_as_float(((uint)u) << 16);
}
static __device__ __forceinline__ uint pk(ushort a, ushort b) {
    return (uint)a | ((uint)b << 16);
}

static __device__ __forceinline__ void gl_lds16(const void* g, void* l) {
    __builtin_amdgcn_global_load_lds(
        (const __attribute__((address_space(1))) uint*)(uintptr_t)g,
        (__attribute__((address_space(3))) uint*)(uintptr_t)l, 16, 0, 0);
}

// ---------------- CSR build ----------------
__global__ void k_deg(const int* __restrict__ edges, int* __restrict__ deg) {
    int e = blockIdx.x * blockDim.x + threadIdx.x;
    if (e < NE) atomicAdd(&deg[edges[2 * e + 1]], 1);
}

__global__ void k_off(const int* __restrict__ deg, int* __restrict__ off,
                      int* __restrict__ cur, int* __restrict__ counter) {
    int v = blockIdx.x * blockDim.x + threadIdx.x;
    if (v < NN) {
        int o = atomicAdd(counter, deg[v]);
        off[v] = o;
        cur[v] = o;
    }
}

__global__ void k_fill(const int* __restrict__ edges, int* __restrict__ cur,
                       int* __restrict__ csr_src) {
    int e = blockIdx.x * blockDim.x + threadIdx.x;
    if (e < NE) {
        int s = edges[2 * e];
        int d = edges[2 * e + 1];
        int pos = atomicAdd(&cur[d], 1);
        csr_src[pos] = s;
    }
}

// ---------------- combined weights (f32) ----------------
// B1[t][k][n] = sum_j W_ih[t][n][j] * W_msg[t][j][k]   (k<256, n<384)
__global__ void k_comb1(const float* __restrict__ W_ih, const float* __restrict__ W_msg,
                        float* __restrict__ B1) {
    int idx = blockIdx.x * blockDim.x + threadIdx.x;
    if (idx >= 2 * K2 * G3) return;
    int k = idx % K2;
    int n = (idx / K2) % G3;
    int t = idx / (K2 * G3);
    const float* wi = W_ih + ((size_t)t * G3 + n) * K2;
    const float* wm = W_msg + (size_t)t * K2 * K2;
    float acc = 0.f;
#pragma unroll 8
    for (int j = 0; j < K2; j++) acc += wi[j] * wm[(size_t)j * K2 + k];
    B1[((size_t)t * K2 + k) * G3 + n] = acc;
}

// c3[t][n] = sum_j W_ih[t][n][j] * b_msg[t][j]
__global__ void k_comb3(const float* __restrict__ W_ih, const float* __restrict__ b_msg,
                        float* __restrict__ c3) {
    int idx = blockIdx.x * blockDim.x + threadIdx.x;
    if (idx >= 2 * G3) return;
    int n = idx % G3;
    int t = idx / G3;
    const float* wi = W_ih + ((size_t)t * G3 + n) * K2;
    const float* bm = b_msg + t * K2;
    float acc = 0.f;
#pragma unroll 8
    for (int j = 0; j < K2; j++) acc += wi[j] * bm[j];
    c3[idx] = acc;
}

// ---------------- pack B per 16-col slice (bf16) ----------------
// Bq[t][slice(8)][slot(48)][lane(64)][e(8)]
// slot = slab*12 + kb*3 + gate ; slab: 0=C1, 1=C2_hi, 2=C2_lo, 3=W_hh
// out col d = slice*16 + (lane&15) ; frag k = kb*32 + (lane>>4)*8 + e (128-k slab)
__global__ void k_pack5(const float* __restrict__ B1, const float* __restrict__ W_hh,
                        ushort* __restrict__ Bq) {
    int idx = blockIdx.x * blockDim.x + threadIdx.x;
    if (idx >= 2 * 8 * 48 * 64) return;
    int lane = idx & 63;
    int slot = (idx >> 6) % 48;
    int slice = ((idx >> 6) / 48) % 8;
    int t = idx / (64 * 48 * 8);
    int slab = slot / 12;
    int rem = slot % 12;
    int kb = rem / 3, gate = rem % 3;
    int d = slice * 16 + (lane & 15);
    int kbase = kb * 32 + (lane >> 4) * 8;
    ushort* dst = Bq + (size_t)idx * 8;
#pragma unroll
    for (int e = 0; e < 8; e++) {
        int k = kbase + e;  // 0..127 within slab
        float v;
        if (slab == 0) {
            v = B1[((size_t)t * K2 + k) * G3 + gate * 128 + d];
        } else if (slab == 3) {
            v = W_hh[((size_t)t * G3 + gate * 128 + d) * HD + k];
        } else {
            float full = B1[((size_t)t * K2 + 128 + k) * G3 + gate * 128 + d];
            v = (slab == 1) ? full : (full - b2f(f2b(full)));
        }
        dst[e] = f2b(v);
    }
}

// bias packs, each [t][slice(8)][3][16]
__global__ void k_packbias4(const float* __restrict__ b_ih, const float* __restrict__ b_hh,
                            const float* __restrict__ c3,
                            float* __restrict__ bih_p, float* __restrict__ bhh_p,
                            float* __restrict__ c3_p) {
    int idx = blockIdx.x * blockDim.x + threadIdx.x;
    if (idx >= 2 * 8 * 3 * 16) return;
    int c = idx & 15;
    int g = (idx >> 4) % 3;
    int slice = ((idx >> 4) / 3) % 8;
    int t = idx / (16 * 3 * 8);
    int d = slice * 16 + c;
    bih_p[idx] = b_ih[t * G3 + g * 128 + d];
    bhh_p[idx] = b_hh[t * G3 + g * 128 + d];
    c3_p[idx]  = c3[t * G3 + g * 128 + d];
}

// ---------------- h f32 -> bf16 (for gathers) ----------------
__global__ void k_h2b(const float* __restrict__ h, ushort* __restrict__ hb) {
    int i = blockIdx.x * blockDim.x + threadIdx.x;
    if (i >= NN * HD / 4) return;
    float4 v = reinterpret_cast<const float4*>(h)[i];
    ushort4 o;
    o.x = f2b(v.x); o.y = f2b(v.y); o.z = f2b(v.z); o.w = f2b(v.w);
    reinterpret_cast<ushort4*>(hb)[i] = o;
}

// ---------------- prep: gather + write A [s | dh_hi | dh_lo | h_hi] frag order ----------------
// FA[tile(3125)][slab(4)][kb(4)][lane(64)][e(8)] bf16  (tile = 4096 uints)
// node wv = tile*16 + r: kb = lane>>4 ; lp = r + 16*((lane&15)>>2) ; uint = lp*4+(lane&3)
__global__ void k_prep(const ushort* __restrict__ hb, const float* __restrict__ hf,
                       const int* __restrict__ off, const int* __restrict__ deg,
                       const int* __restrict__ csr, ushort* __restrict__ FA) {
    int wv = (blockIdx.x * blockDim.x + threadIdx.x) >> 6;
    int lane = threadIdx.x & 63;
    if (wv >= NN) return;
    int st = off[wv];
    int dg = deg[wv];
    float a0 = 0.f, a1 = 0.f;
    int j = 0;
    for (; j + 16 <= dg; j += 16) {
        uint v[16];
#pragma unroll
        for (int q = 0; q < 16; q++) {
            int s = csr[st + j + q];
            v[q] = *reinterpret_cast<const uint*>(hb + (size_t)s * HD + lane * 2);
        }
#pragma unroll
        for (int q = 0; q < 16; q++) {
            a0 += b2f((ushort)(v[q] & 0xffff));
            a1 += b2f((ushort)(v[q] >> 16));
        }
    }
    for (; j + 4 <= dg; j += 4) {
        uint v[4];
#pragma unroll
        for (int q = 0; q < 4; q++) {
            int s = csr[st + j + q];
            v[q] = *reinterpret_cast<const uint*>(hb + (size_t)s * HD + lane * 2);
        }
#pragma unroll
        for (int q = 0; q < 4; q++) {
            a0 += b2f((ushort)(v[q] & 0xffff));
            a1 += b2f((ushort)(v[q] >> 16));
        }
    }
    for (; j < dg; j++) {
        int s = csr[st + j];
        uint v = *reinterpret_cast<const uint*>(hb + (size_t)s * HD + lane * 2);
        a0 += b2f((ushort)(v & 0xffff));
        a1 += b2f((ushort)(v >> 16));
    }
    int tile = wv >> 4, r = wv & 15;
    int kb = lane >> 4;
    int lp = r + (((lane & 15) >> 2) << 4);
    uint* base = reinterpret_cast<uint*>(FA) + (size_t)tile * 4096 + kb * 256 +
                 lp * 4 + (lane & 3);
    float2 hv = *reinterpret_cast<const float2*>(hf + (size_t)wv * HD + lane * 2);
    float dgf = (float)dg;
    float dh0 = dgf * hv.x, dh1 = dgf * hv.y;
    ushort p0 = f2b(dh0), p1 = f2b(dh1);
    ushort l0 = f2b(dh0 - b2f(p0)), l1 = f2b(dh1 - b2f(p1));
    base[0]    = pk(f2b(a0), f2b(a1));        // slab 0: s
    base[1024] = pk(p0, p1);                  // slab 1: dh_hi
    base[2048] = pk(l0, l1);                  // slab 2: dh_lo
    base[3072] = pk(f2b(hv.x), f2b(hv.y));    // slab 3: h_hi
}

// ---------------- fused MFMA GEMM + GRU: one barrier, slice-resident B ----------------
// Block 256 thr (4 waves) = 64 rows x one 16-col slice (all 6 gates).
// Round-7 math exactly: accI = C1*s + C2hi*dh_hi + C2hi*dh_lo + C2lo*dh_hi,
// accH = Whh*h_hi. Epilogue identical to round 7 (no division).
#define BS(slab, kb, nf) \
    (*reinterpret_cast<const s16x8*>(&Bs[(size_t)((((slab) * 12 + (kb) * 3 + (nf)) * 64 + lane)) * 8]))

__global__ __launch_bounds__(256) void k_fused(
    const ushort* __restrict__ FA,      // [3125][16][64][8] bf16 frag-order A
    const ushort* __restrict__ Bq_t,    // [8][48][512] bf16 (this t)
    const float* __restrict__ bih_t,    // [8][3][16]
    const float* __restrict__ bhh_t,
    const float* __restrict__ c3_t,
    const int* __restrict__ deg,
    const float* __restrict__ hcur,     // [NN][128] f32
    float* __restrict__ hout,           // [NN][128] f32
    ushort* __restrict__ hb_out)        // [NN][128] bf16
{
    __shared__ __align__(16) ushort Bs[48 * 512];

    int tid = threadIdx.x;
    int L = blockIdx.x;
    int grp = (L & 7) + ((L >> 6) << 3);     // 8 slices of a group share an XCD
    int slice = (L >> 3) & 7;
    if (grp >= NGRP) return;
    int w = tid >> 6;
    int lane = tid & 63;
    int lhi = lane >> 4;
    int col = lane & 15;
    int rowbase = grp * 64 + w * 16;
    int tile = rowbase >> 4;
    int tclamp = tile < NTILES ? tile : NTILES - 1;

    // stage B slice: 48 segs of 1KB; wave w loads 12
    const ushort* Bg = Bq_t + (size_t)slice * 48 * 512;
#pragma unroll
    for (int i = 0; i < 12; i++) {
        int seg = w * 12 + i;
        gl_lds16(Bg + (size_t)seg * 512 + lane * 8, &Bs[(size_t)seg * 512]);
    }

    // issue all A-frag loads up front (16 x 1KB coalesced)
    const ushort* FAt = FA + (size_t)tclamp * 8192;
    s16x8 As[4], Ahh[4], Ahl[4], Ah[4];
#pragma unroll
    for (int kb = 0; kb < 4; kb++) {
        As[kb]  = *reinterpret_cast<const s16x8*>(FAt + ((size_t)(kb) * 64 + lane) * 8);
        Ahh[kb] = *reinterpret_cast<const s16x8*>(FAt + ((size_t)(4 + kb) * 64 + lane) * 8);
        Ahl[kb] = *reinterpret_cast<const s16x8*>(FAt + ((size_t)(8 + kb) * 64 + lane) * 8);
        Ah[kb]  = *reinterpret_cast<const s16x8*>(FAt + ((size_t)(12 + kb) * 64 + lane) * 8);
    }

    // prefetch epilogue operands
    int d = (slice << 4) + col;
    int rbase0 = rowbase + (lhi << 2);
    float hv[4];
    int dgi[4];
#pragma unroll
    for (int r = 0; r < 4; r++) {
        int m = rbase0 + r;
        int mm = m < NN ? m : 0;
        hv[r] = hcur[(size_t)mm * HD + d];
        dgi[r] = deg[mm];
    }
    float bihv[3], bhhv[3], c3v[3];
#pragma unroll
    for (int g = 0; g < 3; g++) {
        int o = (slice * 3 + g) * 16 + col;
        bihv[g] = bih_t[o];
        bhhv[g] = bhh_t[o];
        c3v[g] = c3_t[o];
    }

    __syncthreads();   // single barrier: B resident (drains all vmcnt)

    f32x4 accI[3], accH[3];
#pragma unroll
    for (int i = 0; i < 3; i++) {
        accI[i] = f32x4{0.f, 0.f, 0.f, 0.f};
        accH[i] = f32x4{0.f, 0.f, 0.f, 0.f};
    }

#pragma unroll
    for (int kb = 0; kb < 4; kb++) {
#pragma unroll
        for (int nf = 0; nf < 3; nf++) {
            s16x8 b0 = BS(0, kb, nf);
            accI[nf] = __builtin_amdgcn_mfma_f32_16x16x32_bf16(As[kb], b0, accI[nf], 0, 0, 0);
            s16x8 b1 = BS(1, kb, nf);
            accI[nf] = __builtin_amdgcn_mfma_f32_16x16x32_bf16(Ahh[kb], b1, accI[nf], 0, 0, 0);
            accI[nf] = __builtin_amdgcn_mfma_f32_16x16x32_bf16(Ahl[kb], b1, accI[nf], 0, 0, 0);
            s16x8 b2 = BS(2, kb, nf);
            accI[nf] = __builtin_amdgcn_mfma_f32_16x16x32_bf16(Ahh[kb], b2, accI[nf], 0, 0, 0);
            s16x8 b3 = BS(3, kb, nf);
            accH[nf] = __builtin_amdgcn_mfma_f32_16x16x32_bf16(Ah[kb], b3, accH[nf], 0, 0, 0);
        }
    }

#pragma unroll
    for (int r = 0; r < 4; r++) {
        int m = rbase0 + r;
        bool wr = m < NN;
        float dgf = (float)dgi[r];
        float ir  = accI[0][r] + dgf * c3v[0] + bihv[0];
        float iz  = accI[1][r] + dgf * c3v[1] + bihv[1];
        float in_ = accI[2][r] + dgf * c3v[2] + bihv[2];
        float hr = accH[0][r] + bhhv[0];
        float hz = accH[1][r] + bhhv[1];
        float hn = accH[2][r] + bhhv[2];
        float rg = 1.f / (1.f + expf(-(ir + hr)));
        float zg = 1.f / (1.f + expf(-(iz + hz)));
        float ng = tanhf(in_ + rg * hn);
        float hnew = (1.f - zg) * ng + zg * hv[r];
        float res = (dgi[r] > 0) ? hnew : hv[r];
        if (wr) {
            hout[(size_t)m * HD + d] = res;
            hb_out[(size_t)m * HD + d] = f2b(res);
        }
    }
}

extern "C" void kernel_launch(void* const* d_in, const int* in_sizes, int n_in,
                              void* d_out, int out_size, void* d_ws, size_t ws_size,
                              hipStream_t stream) {
    const float* h_in  = (const float*)d_in[0];
    const int*   edges = (const int*)d_in[1];
    const float* W_msg = (const float*)d_in[2];
    const float* b_msg = (const float*)d_in[3];
    const float* W_ih  = (const float*)d_in[4];
    const float* W_hh  = (const float*)d_in[5];
    const float* b_ih  = (const float*)d_in[6];
    const float* b_hh  = (const float*)d_in[7];
    float* out = (float*)d_out;

    char* p = (char*)d_ws;
    auto alloc = [&](size_t bytes) {
        void* r = (void*)p;
        p += (bytes + 255) / 256 * 256;
        return r;
    };
    int*    deg     = (int*)alloc((size_t)(NN + 1) * 4);  // +1: counter
    int*    off     = (int*)alloc((size_t)NN * 4);
    int*    cur     = (int*)alloc((size_t)NN * 4);
    int*    csr_src = (int*)alloc((size_t)NE * 4);
    float*  B1      = (float*)alloc((size_t)2 * K2 * G3 * 4);
    float*  c3      = (float*)alloc((size_t)2 * G3 * 4);
    ushort* Bq      = (ushort*)alloc((size_t)2 * 8 * 48 * 512 * 2);
    float*  bih_p   = (float*)alloc((size_t)2 * 8 * 3 * 16 * 4);
    float*  bhh_p   = (float*)alloc((size_t)2 * 8 * 3 * 16 * 4);
    float*  c3_p    = (float*)alloc((size_t)2 * 8 * 3 * 16 * 4);
    ushort* hb0     = (ushort*)alloc((size_t)NN * HD * 2);
    ushort* hb1     = (ushort*)alloc((size_t)NN * HD * 2);
    ushort* FA      = (ushort*)alloc((size_t)NTILES * 8192 * 2);
    float*  h1      = (float*)alloc((size_t)NN * HD * 4);
    int*    counter = deg + NN;

    hipMemsetAsync(deg, 0, (size_t)(NN + 1) * 4, stream);
    k_deg<<<(NE + 255) / 256, 256, 0, stream>>>(edges, deg);
    k_off<<<(NN + 255) / 256, 256, 0, stream>>>(deg, off, cur, counter);
    k_fill<<<(NE + 255) / 256, 256, 0, stream>>>(edges, cur, csr_src);
    k_comb1<<<(2 * K2 * G3 + 255) / 256, 256, 0, stream>>>(W_ih, W_msg, B1);
    k_comb3<<<(2 * G3 + 255) / 256, 256, 0, stream>>>(W_ih, b_msg, c3);
    k_pack5<<<(2 * 8 * 48 * 64 + 255) / 256, 256, 0, stream>>>(B1, W_hh, Bq);
    k_packbias4<<<(2 * 8 * 3 * 16 + 255) / 256, 256, 0, stream>>>(b_ih, b_hh, c3,
                                                                  bih_p, bhh_p, c3_p);
    k_h2b<<<(NN * HD / 4 + 255) / 256, 256, 0, stream>>>(h_in, hb0);

    const int FGRID = 98 * 64;  // 6272 blocks; 16 idle (grp >= 782)
    const size_t BqT = (size_t)8 * 48 * 512;   // ushort units per t
    const size_t biasT = (size_t)8 * 3 * 16;

    // step 0
    k_prep<<<(NN * 64 + 255) / 256, 256, 0, stream>>>(hb0, h_in, off, deg, csr_src, FA);
    k_fused<<<FGRID, 256, 0, stream>>>(FA, Bq, bih_p, bhh_p, c3_p, deg, h_in, h1, hb1);
    // step 1 (hb_out reuses hb0; it is rebuilt by k_h2b every launch)
    k_prep<<<(NN * 64 + 255) / 256, 256, 0, stream>>>(hb1, h1, off, deg, csr_src, FA);
    k_fused<<<FGRID, 256, 0, stream>>>(FA, Bq + BqT, bih_p + biasT, bhh_p + biasT,
                                       c3_p + biasT, deg, h1, out, hb0);
}

// Round 10
// 293.584 us; speedup vs baseline: 2.5121x; 1.1685x over previous
//
#include <hip/hip_runtime.h>
#include <hip/hip_bf16.h>

#define NN 50000
#define NE 800000
#define HD 128
#define G3 384   // 3*H
#define K2 256   // 2*H
#define NTILES 3125  // NN/16 exactly
#define SLOTS 40

typedef short s16x8 __attribute__((ext_vector_type(8)));
typedef float f32x4 __attribute__((ext_vector_type(4)));

static __device__ __forceinline__ ushort f2b(float f) {
    __hip_bfloat16 b = __float2bfloat16(f);
    return *(ushort*)&b;
}
static __device__ __forceinline__ float b2f(ushort u) {
    return __uint_as_float(((uint)u) << 16);
}
static __device__ __forceinline__ uint pk(ushort a, ushort b) {
    return (uint)a | ((uint)b << 16);
}

static __device__ __forceinline__ void gl_lds16(const void* g, void* l) {
    __builtin_amdgcn_global_load_lds(
        (const __attribute__((address_space(1))) uint*)(uintptr_t)g,
        (__attribute__((address_space(3))) uint*)(uintptr_t)l, 16, 0, 0);
}

// ---------------- one-pass CSR build (slots + overflow) ----------------
__global__ void k_fill1(const int* __restrict__ edges, int* __restrict__ cnt,
                        int* __restrict__ slots, uint* __restrict__ ovf,
                        int* __restrict__ ovfc) {
    int e = blockIdx.x * blockDim.x + threadIdx.x;
    if (e >= NE) return;
    int s = edges[2 * e];
    int d = edges[2 * e + 1];
    int pos = atomicAdd(&cnt[d], 1);
    if (pos < SLOTS) {
        slots[d * SLOTS + pos] = s;
    } else {
        int o = atomicAdd(ovfc, 1);
        ovf[o] = ((uint)d << 16) | (uint)s;
    }
}

// ---------------- preprocessing, merged kernel 0 ----------------
// blocks [0,768): B1[t][k][n] = sum_j W_ih[t][n][j]*W_msg[t][j][k]
// block 768..770: c3[t][n] = sum_j W_ih[t][n][j]*b_msg[t][j]
// blocks [771, 771+6250): h2b
__global__ void k_pre0(const float* __restrict__ W_ih, const float* __restrict__ W_msg,
                       const float* __restrict__ b_msg, const float* __restrict__ h,
                       float* __restrict__ B1, float* __restrict__ c3,
                       ushort* __restrict__ hb) {
    int b = blockIdx.x;
    int tid = threadIdx.x;
    if (b < 768) {
        int idx = b * 256 + tid;
        int k = idx % K2;
        int n = (idx / K2) % G3;
        int t = idx / (K2 * G3);
        const float* wi = W_ih + ((size_t)t * G3 + n) * K2;
        const float* wm = W_msg + (size_t)t * K2 * K2;
        float acc = 0.f;
#pragma unroll 8
        for (int j = 0; j < K2; j++) acc += wi[j] * wm[(size_t)j * K2 + k];
        B1[((size_t)t * K2 + k) * G3 + n] = acc;
    } else if (b < 771) {
        int idx = (b - 768) * 256 + tid;
        if (idx >= 2 * G3) return;
        int n = idx % G3;
        int t = idx / G3;
        const float* wi = W_ih + ((size_t)t * G3 + n) * K2;
        const float* bm = b_msg + t * K2;
        float acc = 0.f;
#pragma unroll 8
        for (int j = 0; j < K2; j++) acc += wi[j] * bm[j];
        c3[idx] = acc;
    } else {
        int i = (b - 771) * 256 + tid;
        if (i >= NN * HD / 4) return;
        float4 v = reinterpret_cast<const float4*>(h)[i];
        ushort4 o;
        o.x = f2b(v.x); o.y = f2b(v.y); o.z = f2b(v.z); o.w = f2b(v.w);
        reinterpret_cast<ushort4*>(hb)[i] = o;
    }
}

// ---------------- preprocessing, merged kernel 1 (pack B + biases) ----------------
// Bq[t][slice(8)][slot(48)][lane(64)][e(8)] ; slot = slab*12+kb*3+gate
// slab: 0=C1, 1=C2_hi, 2=C2_lo, 3=W_hh ; d = slice*16+(lane&15) ; k=kb*32+(lane>>4)*8+e
__global__ void k_pre1(const float* __restrict__ B1, const float* __restrict__ W_hh,
                       const float* __restrict__ b_ih, const float* __restrict__ b_hh,
                       const float* __restrict__ c3, ushort* __restrict__ Bq,
                       float* __restrict__ bih_p, float* __restrict__ bhh_p,
                       float* __restrict__ c3_p) {
    int b = blockIdx.x;
    int tid = threadIdx.x;
    if (b < 192) {
        int idx = b * 256 + tid;
        int lane = idx & 63;
        int slot = (idx >> 6) % 48;
        int slice = ((idx >> 6) / 48) % 8;
        int t = idx / (64 * 48 * 8);
        int slab = slot / 12;
        int rem = slot % 12;
        int kb = rem / 3, gate = rem % 3;
        int d = slice * 16 + (lane & 15);
        int kbase = kb * 32 + (lane >> 4) * 8;
        ushort* dst = Bq + (size_t)idx * 8;
#pragma unroll
        for (int e = 0; e < 8; e++) {
            int k = kbase + e;
            float v;
            if (slab == 0) {
                v = B1[((size_t)t * K2 + k) * G3 + gate * 128 + d];
            } else if (slab == 3) {
                v = W_hh[((size_t)t * G3 + gate * 128 + d) * HD + k];
            } else {
                float full = B1[((size_t)t * K2 + 128 + k) * G3 + gate * 128 + d];
                v = (slab == 1) ? full : (full - b2f(f2b(full)));
            }
            dst[e] = f2b(v);
        }
    } else {
        int idx = (b - 192) * 256 + tid;
        if (idx >= 2 * 8 * 3 * 16) return;
        int c = idx & 15;
        int g = (idx >> 4) % 3;
        int slice = ((idx >> 4) / 3) % 8;
        int t = idx / (16 * 3 * 8);
        int d = slice * 16 + c;
        bih_p[idx] = b_ih[t * G3 + g * 128 + d];
        bhh_p[idx] = b_hh[t * G3 + g * 128 + d];
        c3_p[idx]  = c3[t * G3 + g * 128 + d];
    }
}

// ---------------- prep: gather + write A [s | dh_hi | dh_lo | h_hi] frag order ----------------
// FA[tile(3125)][slab(4)][kb(4)][lane(64)][e(8)] bf16  (tile = 4096 uints)
__global__ void k_prep(const ushort* __restrict__ hb, const float* __restrict__ hf,
                       const int* __restrict__ cnt, const int* __restrict__ slots,
                       const uint* __restrict__ ovf, const int* __restrict__ ovfc,
                       ushort* __restrict__ FA) {
    int wv = (blockIdx.x * blockDim.x + threadIdx.x) >> 6;
    int lane = threadIdx.x & 63;
    if (wv >= NN) return;
    int dg = cnt[wv];
    int lim = dg < SLOTS ? dg : SLOTS;
    const int* sl = slots + wv * SLOTS;
    float a0 = 0.f, a1 = 0.f;
    int j = 0;
    for (; j + 16 <= lim; j += 16) {
        uint v[16];
#pragma unroll
        for (int q = 0; q < 16; q++) {
            int s = sl[j + q];
            v[q] = *reinterpret_cast<const uint*>(hb + (size_t)s * HD + lane * 2);
        }
#pragma unroll
        for (int q = 0; q < 16; q++) {
            a0 += b2f((ushort)(v[q] & 0xffff));
            a1 += b2f((ushort)(v[q] >> 16));
        }
    }
    for (; j + 4 <= lim; j += 4) {
        uint v[4];
#pragma unroll
        for (int q = 0; q < 4; q++) {
            int s = sl[j + q];
            v[q] = *reinterpret_cast<const uint*>(hb + (size_t)s * HD + lane * 2);
        }
#pragma unroll
        for (int q = 0; q < 4; q++) {
            a0 += b2f((ushort)(v[q] & 0xffff));
            a1 += b2f((ushort)(v[q] >> 16));
        }
    }
    for (; j < lim; j++) {
        int s = sl[j];
        uint v = *reinterpret_cast<const uint*>(hb + (size_t)s * HD + lane * 2);
        a0 += b2f((ushort)(v & 0xffff));
        a1 += b2f((ushort)(v >> 16));
    }
    if (dg > SLOTS) {
        int oc = *ovfc;
        for (int k = 0; k < oc; k++) {
            uint pr = ovf[k];
            if ((int)(pr >> 16) == wv) {
                int s = (int)(pr & 0xffffu);
                uint v = *reinterpret_cast<const uint*>(hb + (size_t)s * HD + lane * 2);
                a0 += b2f((ushort)(v & 0xffff));
                a1 += b2f((ushort)(v >> 16));
            }
        }
    }
    int tile = wv >> 4, r = wv & 15;
    int kb = lane >> 4;
    int lp = r + (((lane & 15) >> 2) << 4);
    uint* base = reinterpret_cast<uint*>(FA) + (size_t)tile * 4096 + kb * 256 +
                 lp * 4 + (lane & 3);
    float2 hv = *reinterpret_cast<const float2*>(hf + (size_t)wv * HD + lane * 2);
    float dgf = (float)dg;
    float dh0 = dgf * hv.x, dh1 = dgf * hv.y;
    ushort p0 = f2b(dh0), p1 = f2b(dh1);
    ushort l0 = f2b(dh0 - b2f(p0)), l1 = f2b(dh1 - b2f(p1));
    base[0]    = pk(f2b(a0), f2b(a1));        // slab 0: s
    base[1024] = pk(p0, p1);                  // slab 1: dh_hi
    base[2048] = pk(l0, l1);                  // slab 2: dh_lo
    base[3072] = pk(f2b(hv.x), f2b(hv.y));    // slab 3: h_hi
}

// ---------------- fused MFMA GEMM + GRU: octet blocks, slice-resident B ----------------
// 832 blocks = 104 (octet,slice-q) x 8; bid%8 = octet%8 keeps an octet's 8 slices
// on one XCD. Block stages its 48KB B slice once; each of 4 waves loops 8 tiles.
// Math identical to round 9.
#define BS(slab, kb, nf) \
    (*reinterpret_cast<const s16x8*>(&Bs[(size_t)((((slab) * 12 + (kb) * 3 + (nf)) * 64 + lane)) * 8]))

__global__ __launch_bounds__(256) void k_fused(
    const ushort* __restrict__ FA,      // [3125][16][64][8] bf16 frag-order A
    const ushort* __restrict__ Bq_t,    // [8][48][512] bf16 (this t)
    const float* __restrict__ bih_t,    // [8][3][16]
    const float* __restrict__ bhh_t,
    const float* __restrict__ c3_t,
    const int* __restrict__ deg,
    const float* __restrict__ hcur,     // [NN][128] f32
    float* __restrict__ hout,           // [NN][128] f32
    ushort* __restrict__ hb_out)        // [NN][128] bf16
{
    __shared__ __align__(16) ushort Bs[48 * 512];

    int tid = threadIdx.x;
    int bid = blockIdx.x;
    int r8 = bid & 7;
    int q = bid >> 3;
    int oct = (q >> 3) * 8 + r8;    // 0..103 ; valid < 98
    int slice = q & 7;
    if (oct * 32 >= NTILES) return; // whole block exits (uniform)
    int w = tid >> 6;
    int lane = tid & 63;
    int lhi = lane >> 4;
    int col = lane & 15;

    // stage B slice: 48 segs of 1KB; wave w loads 12
    const ushort* Bg = Bq_t + (size_t)slice * 48 * 512;
#pragma unroll
    for (int i = 0; i < 12; i++) {
        int seg = w * 12 + i;
        gl_lds16(Bg + (size_t)seg * 512 + lane * 8, &Bs[(size_t)seg * 512]);
    }

    int d = (slice << 4) + col;
    float bihv[3], bhhv[3], c3v[3];
#pragma unroll
    for (int g = 0; g < 3; g++) {
        int o = (slice * 3 + g) * 16 + col;
        bihv[g] = bih_t[o];
        bhhv[g] = bhh_t[o];
        c3v[g] = c3_t[o];
    }

    __syncthreads();   // single barrier: B resident (drains vmcnt)

    for (int it = 0; it < 8; it++) {
        int t = oct * 32 + w + 4 * it;   // wave-uniform
        if (t >= NTILES) break;
        const ushort* FAt = FA + (size_t)t * 8192;

        s16x8 As[4], Ahh[4], Ahl[4], Ah[4];
#pragma unroll
        for (int kb = 0; kb < 4; kb++) {
            As[kb]  = *reinterpret_cast<const s16x8*>(FAt + ((size_t)(kb) * 64 + lane) * 8);
            Ahh[kb] = *reinterpret_cast<const s16x8*>(FAt + ((size_t)(4 + kb) * 64 + lane) * 8);
            Ahl[kb] = *reinterpret_cast<const s16x8*>(FAt + ((size_t)(8 + kb) * 64 + lane) * 8);
            Ah[kb]  = *reinterpret_cast<const s16x8*>(FAt + ((size_t)(12 + kb) * 64 + lane) * 8);
        }

        int rbase0 = t * 16 + (lhi << 2);
        float hv[4];
        int dgi[4];
#pragma unroll
        for (int r = 0; r < 4; r++) {
            int m = rbase0 + r;
            int mm = m < NN ? m : 0;
            hv[r] = hcur[(size_t)mm * HD + d];
            dgi[r] = deg[mm];
        }

        f32x4 accI[3], accH[3];
#pragma unroll
        for (int i = 0; i < 3; i++) {
            accI[i] = f32x4{0.f, 0.f, 0.f, 0.f};
            accH[i] = f32x4{0.f, 0.f, 0.f, 0.f};
        }

#pragma unroll
        for (int kb = 0; kb < 4; kb++) {
#pragma unroll
            for (int nf = 0; nf < 3; nf++) {
                s16x8 b0 = BS(0, kb, nf);
                accI[nf] = __builtin_amdgcn_mfma_f32_16x16x32_bf16(As[kb], b0, accI[nf], 0, 0, 0);
                s16x8 b1 = BS(1, kb, nf);
                accI[nf] = __builtin_amdgcn_mfma_f32_16x16x32_bf16(Ahh[kb], b1, accI[nf], 0, 0, 0);
                accI[nf] = __builtin_amdgcn_mfma_f32_16x16x32_bf16(Ahl[kb], b1, accI[nf], 0, 0, 0);
                s16x8 b2 = BS(2, kb, nf);
                accI[nf] = __builtin_amdgcn_mfma_f32_16x16x32_bf16(Ahh[kb], b2, accI[nf], 0, 0, 0);
                s16x8 b3 = BS(3, kb, nf);
                accH[nf] = __builtin_amdgcn_mfma_f32_16x16x32_bf16(Ah[kb], b3, accH[nf], 0, 0, 0);
            }
        }

#pragma unroll
        for (int r = 0; r < 4; r++) {
            int m = rbase0 + r;
            bool wr = m < NN;
            float dgf = (float)dgi[r];
            float ir  = accI[0][r] + dgf * c3v[0] + bihv[0];
            float iz  = accI[1][r] + dgf * c3v[1] + bihv[1];
            float in_ = accI[2][r] + dgf * c3v[2] + bihv[2];
            float hr = accH[0][r] + bhhv[0];
            float hz = accH[1][r] + bhhv[1];
            float hn = accH[2][r] + bhhv[2];
            float rg = 1.f / (1.f + expf(-(ir + hr)));
            float zg = 1.f / (1.f + expf(-(iz + hz)));
            float ng = tanhf(in_ + rg * hn);
            float hnew = (1.f - zg) * ng + zg * hv[r];
            float res = (dgi[r] > 0) ? hnew : hv[r];
            if (wr) {
                hout[(size_t)m * HD + d] = res;
                hb_out[(size_t)m * HD + d] = f2b(res);
            }
        }
    }
}

extern "C" void kernel_launch(void* const* d_in, const int* in_sizes, int n_in,
                              void* d_out, int out_size, void* d_ws, size_t ws_size,
                              hipStream_t stream) {
    const float* h_in  = (const float*)d_in[0];
    const int*   edges = (const int*)d_in[1];
    const float* W_msg = (const float*)d_in[2];
    const float* b_msg = (const float*)d_in[3];
    const float* W_ih  = (const float*)d_in[4];
    const float* W_hh  = (const float*)d_in[5];
    const float* b_ih  = (const float*)d_in[6];
    const float* b_hh  = (const float*)d_in[7];
    float* out = (float*)d_out;

    char* p = (char*)d_ws;
    auto alloc = [&](size_t bytes) {
        void* r = (void*)p;
        p += (bytes + 255) / 256 * 256;
        return r;
    };
    int*    cnt     = (int*)alloc((size_t)(NN + 1) * 4);   // +1: ovf counter
    int*    slots   = (int*)alloc((size_t)NN * SLOTS * 4);
    uint*   ovf     = (uint*)alloc((size_t)NE * 4);
    float*  B1      = (float*)alloc((size_t)2 * K2 * G3 * 4);
    float*  c3      = (float*)alloc((size_t)2 * G3 * 4);
    ushort* Bq      = (ushort*)alloc((size_t)2 * 8 * 48 * 512 * 2);
    float*  bih_p   = (float*)alloc((size_t)2 * 8 * 3 * 16 * 4);
    float*  bhh_p   = (float*)alloc((size_t)2 * 8 * 3 * 16 * 4);
    float*  c3_p    = (float*)alloc((size_t)2 * 8 * 3 * 16 * 4);
    ushort* hb0     = (ushort*)alloc((size_t)NN * HD * 2);
    ushort* hb1     = (ushort*)alloc((size_t)NN * HD * 2);
    ushort* FA      = (ushort*)alloc((size_t)NTILES * 8192 * 2);
    float*  h1      = (float*)alloc((size_t)NN * HD * 4);
    int*    ovfc    = cnt + NN;

    hipMemsetAsync(cnt, 0, (size_t)(NN + 1) * 4, stream);
    k_fill1<<<(NE + 255) / 256, 256, 0, stream>>>(edges, cnt, slots, ovf, ovfc);
    k_pre0<<<771 + (NN * HD / 4 + 255) / 256, 256, 0, stream>>>(
        W_ih, W_msg, b_msg, h_in, B1, c3, hb0);
    k_pre1<<<195, 256, 0, stream>>>(B1, W_hh, b_ih, b_hh, c3, Bq, bih_p, bhh_p, c3_p);

    const int FGRID = 832;
    const size_t BqT = (size_t)8 * 48 * 512;   // ushort units per t
    const size_t biasT = (size_t)8 * 3 * 16;

    // step 0
    k_prep<<<(NN * 64 + 255) / 256, 256, 0, stream>>>(hb0, h_in, cnt, slots, ovf, ovfc, FA);
    k_fused<<<FGRID, 256, 0, stream>>>(FA, Bq, bih_p, bhh_p, c3_p, cnt, h_in, h1, hb1);
    // step 1 (hb_out reuses hb0; it is rebuilt by k_pre0 every launch)
    k_prep<<<(NN * 64 + 255) / 256, 256, 0, stream>>>(hb1, h1, cnt, slots, ovf, ovfc, FA);
    k_fused<<<FGRID, 256, 0, stream>>>(FA, Bq + BqT, bih_p + biasT, bhh_p + biasT,
                                       c3_p + biasT, cnt, h1, out, hb0);
}

// Round 11
// 253.531 us; speedup vs baseline: 2.9090x; 1.1580x over previous
//
#include <hip/hip_runtime.h>
#include <hip/hip_bf16.h>

#define NN 50000
#define NE 800000
#define HD 128
#define G3 384   // 3*H
#define K2 256   // 2*H
#define NTILES 3125  // NN/16 exactly
#define SLOTS 40

typedef short s16x8 __attribute__((ext_vector_type(8)));
typedef float f32x4 __attribute__((ext_vector_type(4)));

static __device__ __forceinline__ ushort f2b(float f) {
    __hip_bfloat16 b = __float2bfloat16(f);
    return *(ushort*)&b;
}
static __device__ __forceinline__ float b2f(ushort u) {
    return __uint_as_float(((uint)u) << 16);
}
static __device__ __forceinline__ uint pk(ushort a, ushort b) {
    return (uint)a | ((uint)b << 16);
}
static __device__ __forceinline__ float fsig(float x) {
    return __builtin_amdgcn_rcpf(1.f + __builtin_amdgcn_exp2f(-x * 1.44269504f));
}
static __device__ __forceinline__ float ftanh(float x) {
    return 1.f - 2.f * __builtin_amdgcn_rcpf(1.f + __builtin_amdgcn_exp2f(x * 2.88539008f));
}

static __device__ __forceinline__ void gl_lds16(const void* g, void* l) {
    __builtin_amdgcn_global_load_lds(
        (const __attribute__((address_space(1))) uint*)(uintptr_t)g,
        (__attribute__((address_space(3))) uint*)(uintptr_t)l, 16, 0, 0);
}

// ---------------- one-pass CSR build (slots + overflow) ----------------
__global__ void k_fill1(const int* __restrict__ edges, int* __restrict__ cnt,
                        ushort* __restrict__ slots, uint* __restrict__ ovf,
                        int* __restrict__ ovfc) {
    int e = blockIdx.x * blockDim.x + threadIdx.x;
    if (e >= NE) return;
    int s = edges[2 * e];
    int d = edges[2 * e + 1];
    int pos = atomicAdd(&cnt[d], 1);
    if (pos < SLOTS) {
        slots[d * SLOTS + pos] = (ushort)s;
    } else {
        int o = atomicAdd(ovfc, 1);
        ovf[o] = ((uint)d << 16) | (uint)s;
    }
}

// ---------------- preprocessing, merged kernel 0 ----------------
__global__ void k_pre0(const float* __restrict__ W_ih, const float* __restrict__ W_msg,
                       const float* __restrict__ b_msg, const float* __restrict__ h,
                       float* __restrict__ B1, float* __restrict__ c3,
                       ushort* __restrict__ hb) {
    int b = blockIdx.x;
    int tid = threadIdx.x;
    if (b < 768) {
        int idx = b * 256 + tid;
        int k = idx % K2;
        int n = (idx / K2) % G3;
        int t = idx / (K2 * G3);
        const float* wi = W_ih + ((size_t)t * G3 + n) * K2;
        const float* wm = W_msg + (size_t)t * K2 * K2;
        float acc = 0.f;
#pragma unroll 8
        for (int j = 0; j < K2; j++) acc += wi[j] * wm[(size_t)j * K2 + k];
        B1[((size_t)t * K2 + k) * G3 + n] = acc;
    } else if (b < 771) {
        int idx = (b - 768) * 256 + tid;
        if (idx >= 2 * G3) return;
        int n = idx % G3;
        int t = idx / G3;
        const float* wi = W_ih + ((size_t)t * G3 + n) * K2;
        const float* bm = b_msg + t * K2;
        float acc = 0.f;
#pragma unroll 8
        for (int j = 0; j < K2; j++) acc += wi[j] * bm[j];
        c3[idx] = acc;
    } else {
        int i = (b - 771) * 256 + tid;
        if (i >= NN * HD / 4) return;
        float4 v = reinterpret_cast<const float4*>(h)[i];
        ushort4 o;
        o.x = f2b(v.x); o.y = f2b(v.y); o.z = f2b(v.z); o.w = f2b(v.w);
        reinterpret_cast<ushort4*>(hb)[i] = o;
    }
}

// ---------------- preprocessing, merged kernel 1 (pack B + biases) ----------------
__global__ void k_pre1(const float* __restrict__ B1, const float* __restrict__ W_hh,
                       const float* __restrict__ b_ih, const float* __restrict__ b_hh,
                       const float* __restrict__ c3, ushort* __restrict__ Bq,
                       float* __restrict__ bih_p, float* __restrict__ bhh_p,
                       float* __restrict__ c3_p) {
    int b = blockIdx.x;
    int tid = threadIdx.x;
    if (b < 192) {
        int idx = b * 256 + tid;
        int lane = idx & 63;
        int slot = (idx >> 6) % 48;
        int slice = ((idx >> 6) / 48) % 8;
        int t = idx / (64 * 48 * 8);
        int slab = slot / 12;
        int rem = slot % 12;
        int kb = rem / 3, gate = rem % 3;
        int d = slice * 16 + (lane & 15);
        int kbase = kb * 32 + (lane >> 4) * 8;
        ushort* dst = Bq + (size_t)idx * 8;
#pragma unroll
        for (int e = 0; e < 8; e++) {
            int k = kbase + e;
            float v;
            if (slab == 0) {
                v = B1[((size_t)t * K2 + k) * G3 + gate * 128 + d];
            } else if (slab == 3) {
                v = W_hh[((size_t)t * G3 + gate * 128 + d) * HD + k];
            } else {
                float full = B1[((size_t)t * K2 + 128 + k) * G3 + gate * 128 + d];
                v = (slab == 1) ? full : (full - b2f(f2b(full)));
            }
            dst[e] = f2b(v);
        }
    } else {
        int idx = (b - 192) * 256 + tid;
        if (idx >= 2 * 8 * 3 * 16) return;
        int c = idx & 15;
        int g = (idx >> 4) % 3;
        int slice = ((idx >> 4) / 3) % 8;
        int t = idx / (16 * 3 * 8);
        int d = slice * 16 + c;
        bih_p[idx] = b_ih[t * G3 + g * 128 + d];
        bhh_p[idx] = b_hh[t * G3 + g * 128 + d];
        c3_p[idx]  = c3[t * G3 + g * 128 + d];
    }
}

// ---------------- prep: gather + write A [s | dh_hi | dh_lo | h_hi] frag order ----------------
__global__ void k_prep(const ushort* __restrict__ hb, const float* __restrict__ hf,
                       const int* __restrict__ cnt, const ushort* __restrict__ slots,
                       const uint* __restrict__ ovf, const int* __restrict__ ovfc,
                       ushort* __restrict__ FA) {
    int wv = (blockIdx.x * blockDim.x + threadIdx.x) >> 6;
    int lane = threadIdx.x & 63;
    if (wv >= NN) return;
    int dg = cnt[wv];
    int lim = dg < SLOTS ? dg : SLOTS;
    const ushort* sl = slots + wv * SLOTS;
    float a0 = 0.f, a1 = 0.f;
    int j = 0;
    for (; j + 16 <= lim; j += 16) {
        uint v[16];
#pragma unroll
        for (int q = 0; q < 16; q++) {
            int s = sl[j + q];
            v[q] = *reinterpret_cast<const uint*>(hb + (size_t)s * HD + lane * 2);
        }
#pragma unroll
        for (int q = 0; q < 16; q++) {
            a0 += b2f((ushort)(v[q] & 0xffff));
            a1 += b2f((ushort)(v[q] >> 16));
        }
    }
    for (; j + 4 <= lim; j += 4) {
        uint v[4];
#pragma unroll
        for (int q = 0; q < 4; q++) {
            int s = sl[j + q];
            v[q] = *reinterpret_cast<const uint*>(hb + (size_t)s * HD + lane * 2);
        }
#pragma unroll
        for (int q = 0; q < 4; q++) {
            a0 += b2f((ushort)(v[q] & 0xffff));
            a1 += b2f((ushort)(v[q] >> 16));
        }
    }
    for (; j < lim; j++) {
        int s = sl[j];
        uint v = *reinterpret_cast<const uint*>(hb + (size_t)s * HD + lane * 2);
        a0 += b2f((ushort)(v & 0xffff));
        a1 += b2f((ushort)(v >> 16));
    }
    if (dg > SLOTS) {
        int oc = *ovfc;
        for (int k = 0; k < oc; k++) {
            uint pr = ovf[k];
            if ((int)(pr >> 16) == wv) {
                int s = (int)(pr & 0xffffu);
                uint v = *reinterpret_cast<const uint*>(hb + (size_t)s * HD + lane * 2);
                a0 += b2f((ushort)(v & 0xffff));
                a1 += b2f((ushort)(v >> 16));
            }
        }
    }
    int tile = wv >> 4, r = wv & 15;
    int kb = lane >> 4;
    int lp = r + (((lane & 15) >> 2) << 4);
    uint* base = reinterpret_cast<uint*>(FA) + (size_t)tile * 4096 + kb * 256 +
                 lp * 4 + (lane & 3);
    float2 hv = *reinterpret_cast<const float2*>(hf + (size_t)wv * HD + lane * 2);
    float dgf = (float)dg;
    float dh0 = dgf * hv.x, dh1 = dgf * hv.y;
    ushort p0 = f2b(dh0), p1 = f2b(dh1);
    ushort l0 = f2b(dh0 - b2f(p0)), l1 = f2b(dh1 - b2f(p1));
    base[0]    = pk(f2b(a0), f2b(a1));        // slab 0: s
    base[1024] = pk(p0, p1);                  // slab 1: dh_hi
    base[2048] = pk(l0, l1);                  // slab 2: dh_lo
    base[3072] = pk(f2b(hv.x), f2b(hv.y));    // slab 3: h_hi
}

// ---------------- fused MFMA GEMM + GRU: 8-wave octet blocks ----------------
// 832 blocks x 512 thr; block = (oct: 32 tiles, slice); 8 waves x 4 tiles.
// bid&7 = oct%8 keeps an octet's 8 slices on one XCD. Math identical to round 10;
// transcendentals via HW exp2/rcp.
#define BS(slab, kb, nf) \
    (*reinterpret_cast<const s16x8*>(&Bs[(size_t)((((slab) * 12 + (kb) * 3 + (nf)) * 64 + lane)) * 8]))

__global__ __launch_bounds__(512) void k_fused(
    const ushort* __restrict__ FA,      // [3125][16][64][8] bf16 frag-order A
    const ushort* __restrict__ Bq_t,    // [8][48][512] bf16 (this t)
    const float* __restrict__ bih_t,    // [8][3][16]
    const float* __restrict__ bhh_t,
    const float* __restrict__ c3_t,
    const int* __restrict__ deg,
    const float* __restrict__ hcur,     // [NN][128] f32
    float* __restrict__ hout,           // [NN][128] f32
    ushort* __restrict__ hb_out)        // [NN][128] bf16
{
    __shared__ __align__(16) ushort Bs[48 * 512];

    int tid = threadIdx.x;
    int bid = blockIdx.x;
    int r8 = bid & 7;
    int q = bid >> 3;
    int oct = (q >> 3) * 8 + r8;    // 0..103 ; valid < 98
    int slice = q & 7;
    if (oct * 32 >= NTILES) return; // whole block exits (uniform)
    int w = tid >> 6;               // 0..7
    int lane = tid & 63;
    int lhi = lane >> 4;
    int col = lane & 15;

    // stage B slice: 48 segs of 1KB; wave w loads 6
    const ushort* Bg = Bq_t + (size_t)slice * 48 * 512;
#pragma unroll
    for (int i = 0; i < 6; i++) {
        int seg = w * 6 + i;
        gl_lds16(Bg + (size_t)seg * 512 + lane * 8, &Bs[(size_t)seg * 512]);
    }

    int d = (slice << 4) + col;
    float bihv[3], bhhv[3], c3v[3];
#pragma unroll
    for (int g = 0; g < 3; g++) {
        int o = (slice * 3 + g) * 16 + col;
        bihv[g] = bih_t[o];
        bhhv[g] = bhh_t[o];
        c3v[g] = c3_t[o];
    }

    __syncthreads();   // single barrier: B resident (drains vmcnt)

#pragma unroll
    for (int it = 0; it < 4; it++) {
        int t = oct * 32 + w + 8 * it;   // wave-uniform
        if (t >= NTILES) break;
        const ushort* FAt = FA + (size_t)t * 8192;

        s16x8 As[4], Ahh[4], Ahl[4], Ah[4];
#pragma unroll
        for (int kb = 0; kb < 4; kb++) {
            As[kb]  = *reinterpret_cast<const s16x8*>(FAt + ((size_t)(kb) * 64 + lane) * 8);
            Ahh[kb] = *reinterpret_cast<const s16x8*>(FAt + ((size_t)(4 + kb) * 64 + lane) * 8);
            Ahl[kb] = *reinterpret_cast<const s16x8*>(FAt + ((size_t)(8 + kb) * 64 + lane) * 8);
            Ah[kb]  = *reinterpret_cast<const s16x8*>(FAt + ((size_t)(12 + kb) * 64 + lane) * 8);
        }

        int rbase0 = t * 16 + (lhi << 2);
        float hv[4];
        int dgi[4];
#pragma unroll
        for (int r = 0; r < 4; r++) {
            int m = rbase0 + r;
            int mm = m < NN ? m : 0;
            hv[r] = hcur[(size_t)mm * HD + d];
            dgi[r] = deg[mm];
        }

        f32x4 accI[3], accH[3];
#pragma unroll
        for (int i = 0; i < 3; i++) {
            accI[i] = f32x4{0.f, 0.f, 0.f, 0.f};
            accH[i] = f32x4{0.f, 0.f, 0.f, 0.f};
        }

#pragma unroll
        for (int kb = 0; kb < 4; kb++) {
#pragma unroll
            for (int nf = 0; nf < 3; nf++) {
                s16x8 b0 = BS(0, kb, nf);
                accI[nf] = __builtin_amdgcn_mfma_f32_16x16x32_bf16(As[kb], b0, accI[nf], 0, 0, 0);
                s16x8 b1 = BS(1, kb, nf);
                accI[nf] = __builtin_amdgcn_mfma_f32_16x16x32_bf16(Ahh[kb], b1, accI[nf], 0, 0, 0);
                accI[nf] = __builtin_amdgcn_mfma_f32_16x16x32_bf16(Ahl[kb], b1, accI[nf], 0, 0, 0);
                s16x8 b2 = BS(2, kb, nf);
                accI[nf] = __builtin_amdgcn_mfma_f32_16x16x32_bf16(Ahh[kb], b2, accI[nf], 0, 0, 0);
                s16x8 b3 = BS(3, kb, nf);
                accH[nf] = __builtin_amdgcn_mfma_f32_16x16x32_bf16(Ah[kb], b3, accH[nf], 0, 0, 0);
            }
        }

#pragma unroll
        for (int r = 0; r < 4; r++) {
            int m = rbase0 + r;
            bool wr = m < NN;
            float dgf = (float)dgi[r];
            float ir  = accI[0][r] + dgf * c3v[0] + bihv[0];
            float iz  = accI[1][r] + dgf * c3v[1] + bihv[1];
            float in_ = accI[2][r] + dgf * c3v[2] + bihv[2];
            float hr = accH[0][r] + bhhv[0];
            float hz = accH[1][r] + bhhv[1];
            float hn = accH[2][r] + bhhv[2];
            float rg = fsig(ir + hr);
            float zg = fsig(iz + hz);
            float ng = ftanh(in_ + rg * hn);
            float hnew = (1.f - zg) * ng + zg * hv[r];
            float res = (dgi[r] > 0) ? hnew : hv[r];
            if (wr) {
                hout[(size_t)m * HD + d] = res;
                hb_out[(size_t)m * HD + d] = f2b(res);
            }
        }
    }
}

extern "C" void kernel_launch(void* const* d_in, const int* in_sizes, int n_in,
                              void* d_out, int out_size, void* d_ws, size_t ws_size,
                              hipStream_t stream) {
    const float* h_in  = (const float*)d_in[0];
    const int*   edges = (const int*)d_in[1];
    const float* W_msg = (const float*)d_in[2];
    const float* b_msg = (const float*)d_in[3];
    const float* W_ih  = (const float*)d_in[4];
    const float* W_hh  = (const float*)d_in[5];
    const float* b_ih  = (const float*)d_in[6];
    const float* b_hh  = (const float*)d_in[7];
    float* out = (float*)d_out;

    char* p = (char*)d_ws;
    auto alloc = [&](size_t bytes) {
        void* r = (void*)p;
        p += (bytes + 255) / 256 * 256;
        return r;
    };
    int*    cnt     = (int*)alloc((size_t)(NN + 1) * 4);   // +1: ovf counter
    ushort* slots   = (ushort*)alloc((size_t)NN * SLOTS * 2);
    uint*   ovf     = (uint*)alloc((size_t)NE * 4);
    float*  B1      = (float*)alloc((size_t)2 * K2 * G3 * 4);
    float*  c3      = (float*)alloc((size_t)2 * G3 * 4);
    ushort* Bq      = (ushort*)alloc((size_t)2 * 8 * 48 * 512 * 2);
    float*  bih_p   = (float*)alloc((size_t)2 * 8 * 3 * 16 * 4);
    float*  bhh_p   = (float*)alloc((size_t)2 * 8 * 3 * 16 * 4);
    float*  c3_p    = (float*)alloc((size_t)2 * 8 * 3 * 16 * 4);
    ushort* hb0     = (ushort*)alloc((size_t)NN * HD * 2);
    ushort* hb1     = (ushort*)alloc((size_t)NN * HD * 2);
    ushort* FA      = (ushort*)alloc((size_t)NTILES * 8192 * 2);
    float*  h1      = (float*)alloc((size_t)NN * HD * 4);
    int*    ovfc    = cnt + NN;

    hipMemsetAsync(cnt, 0, (size_t)(NN + 1) * 4, stream);
    k_fill1<<<(NE + 255) / 256, 256, 0, stream>>>(edges, cnt, slots, ovf, ovfc);
    k_pre0<<<771 + (NN * HD / 4 + 255) / 256, 256, 0, stream>>>(
        W_ih, W_msg, b_msg, h_in, B1, c3, hb0);
    k_pre1<<<195, 256, 0, stream>>>(B1, W_hh, b_ih, b_hh, c3, Bq, bih_p, bhh_p, c3_p);

    const int FGRID = 832;
    const size_t BqT = (size_t)8 * 48 * 512;   // ushort units per t
    const size_t biasT = (size_t)8 * 3 * 16;

    // step 0
    k_prep<<<(NN * 64 + 255) / 256, 256, 0, stream>>>(hb0, h_in, cnt, slots, ovf, ovfc, FA);
    k_fused<<<FGRID, 512, 0, stream>>>(FA, Bq, bih_p, bhh_p, c3_p, cnt, h_in, h1, hb1);
    // step 1 (hb_out reuses hb0; it is rebuilt by k_pre0 every launch)
    k_prep<<<(NN * 64 + 255) / 256, 256, 0, stream>>>(hb1, h1, cnt, slots, ovf, ovfc, FA);
    k_fused<<<FGRID, 512, 0, stream>>>(FA, Bq + BqT, bih_p + biasT, bhh_p + biasT,
                                       c3_p + biasT, cnt, h1, out, hb0);
}